// Round 2
// baseline (201.395 us; speedup 1.0000x reference)
//
#include <hip/hip_runtime.h>

namespace {

constexpr float FF[12] = {0.0144f, 0.0272f, 0.0526f, 0.0972f, 0.193f, 0.63f,
                          -0.63f, -0.193f, -0.0972f, -0.0526f, -0.0272f, -0.0144f};
constexpr float SQ2   = 1.41421356237309515f;
constexpr float NISQ2 = -0.70710678118654752f;

__device__ __forceinline__ void fma4(float4& o, float s, const float4& v) {
  o.x += s * v.x; o.y += s * v.y; o.z += s * v.z; o.w += s * v.w;
}

}  // namespace

// ---------------- Stage 1: fbrec(Y0, Y1, '2c', 'per') -> x (8,64,128,256) ----------------
// 512 threads, 2 blocks/CU (LDS 67.6 KB). One block per plane, 512 planes.
// LDS layout: 128 rows x 33 float4 groups (32 data + 1 pad). Row stride 132 floats.
__global__ __launch_bounds__(512, 4) void s1_kernel(
    const float* __restrict__ y0, const float* __restrict__ y1,
    const float* __restrict__ y2, const float* __restrict__ y3,
    float* __restrict__ xout) {
  __shared__ float bufF[128 * 132];
  float4* buf4 = reinterpret_cast<float4*>(bufF);
  constexpr int SG = 33;  // row stride in float4 groups

  const int p  = blockIdx.x;   // 0..511
  const int b  = p >> 6;
  const int cc = p & 63;
  const int sub = (b * 32 + (cc & 31)) << 14;
  const float* Y0 = (cc < 32 ? y1 : y2) + sub;
  const float* Y1 = (cc < 32 ? y0 : y3) + sub;
  const float4* Y04 = reinterpret_cast<const float4*>(Y0);
  const float4* Y14 = reinterpret_cast<const float4*>(Y1);
  float4* xp4 = reinterpret_cast<float4*>(xout + (size_t)p * 32768);

  const int tid = threadIdx.x;

  // P0: load Y0 plane -> buf
#pragma unroll
  for (int k = 0; k < 8; ++k) {
    int idx = tid + k * 512;
    buf4[(idx >> 5) * SG + (idx & 31)] = Y04[idx];
  }
  __syncthreads();

  // P1: vconv offset-5 (periodic rows), 8-row strips, register window
  {
    const int j4 = tid & 31;
    const int i0 = (tid >> 5) * 8;
    float4 acc[8];
#pragma unroll
    for (int k = 0; k < 8; ++k) acc[k] = make_float4(0.f, 0.f, 0.f, 0.f);
#pragma unroll
    for (int d = 0; d < 19; ++d) {
      int r = (i0 - 5 + d) & 127;
      float4 v = buf4[r * SG + j4];
#pragma unroll
      for (int k = 0; k < 8; ++k) {
        int a = d - k;
        if (a >= 0 && a < 12) fma4(acc[k], FF[a], v);
      }
    }
    __syncthreads();
#pragma unroll
    for (int k = 0; k < 8; ++k) buf4[(i0 + k) * SG + j4] = acc[k];
  }
  __syncthreads();

  // P2: p1 = -1/sqrt2 * (Y1 + hconv offset-5), 8 consecutive groups/thread
  {
    const int i  = tid >> 2;
    const int g0 = (tid & 3) * 8;
    float w[48];
#pragma unroll
    for (int d = 0; d < 12; ++d) {
      float4 v = buf4[i * SG + ((g0 - 2 + d) & 31)];
      w[4 * d + 0] = v.x; w[4 * d + 1] = v.y; w[4 * d + 2] = v.z; w[4 * d + 3] = v.w;
    }
    float4 pv[8];
#pragma unroll
    for (int mg = 0; mg < 8; ++mg) {
      float4 yv = Y14[i * 32 + g0 + mg];
      float o0 = 0.f, o1 = 0.f, o2 = 0.f, o3 = 0.f;
#pragma unroll
      for (int a = 0; a < 12; ++a) {
        const float fa = FF[a];
        o0 += fa * w[3 + 4 * mg + 0 + a];
        o1 += fa * w[3 + 4 * mg + 1 + a];
        o2 += fa * w[3 + 4 * mg + 2 + a];
        o3 += fa * w[3 + 4 * mg + 3 + a];
      }
      pv[mg].x = NISQ2 * (yv.x + o0);
      pv[mg].y = NISQ2 * (yv.y + o1);
      pv[mg].z = NISQ2 * (yv.z + o2);
      pv[mg].w = NISQ2 * (yv.w + o3);
    }
    __syncthreads();
#pragma unroll
    for (int mg = 0; mg < 8; ++mg) buf4[i * SG + g0 + mg] = pv[mg];
  }
  __syncthreads();

  // P3: gather odd-J outputs from p1 into regs; then vconv offset-6 of p1
  float xodd[32];
  {
#pragma unroll
    for (int k = 0; k < 16; ++k) {
      int t = tid + k * 512;            // final-write float4 group id
      int i2 = t >> 6;
      int j4o = t & 63;
      int m0 = 1 - (i2 & 1);
#pragma unroll
      for (int h = 0; h < 2; ++h) {
        int jo = 4 * j4o + m0 + 2 * h;
        int J = (i2 + jo) & 255;
        int c = J >> 1;
        int r = (i2 - 1 - c) & 127;
        xodd[2 * k + h] = bufF[r * 132 + c];
      }
    }
    const int j4 = tid & 31;
    const int i0 = (tid >> 5) * 8;
    float4 acc[8];
#pragma unroll
    for (int k = 0; k < 8; ++k) acc[k] = make_float4(0.f, 0.f, 0.f, 0.f);
#pragma unroll
    for (int d = 0; d < 19; ++d) {
      int r = (i0 - 6 + d) & 127;
      float4 v = buf4[r * SG + j4];
#pragma unroll
      for (int k = 0; k < 8; ++k) {
        int a = d - k;
        if (a >= 0 && a < 12) fma4(acc[k], FF[a], v);
      }
    }
    __syncthreads();
#pragma unroll
    for (int k = 0; k < 8; ++k) buf4[(i0 + k) * SG + j4] = acc[k];
  }
  __syncthreads();

  // P4: p0 = sqrt2*Y0 + hconv offset-6
  {
    const int i  = tid >> 2;
    const int g0 = (tid & 3) * 8;
    float w[48];
#pragma unroll
    for (int d = 0; d < 12; ++d) {
      float4 v = buf4[i * SG + ((g0 - 2 + d) & 31)];
      w[4 * d + 0] = v.x; w[4 * d + 1] = v.y; w[4 * d + 2] = v.z; w[4 * d + 3] = v.w;
    }
    float4 pv[8];
#pragma unroll
    for (int mg = 0; mg < 8; ++mg) {
      float4 yv = Y04[i * 32 + g0 + mg];
      float o0 = 0.f, o1 = 0.f, o2 = 0.f, o3 = 0.f;
#pragma unroll
      for (int a = 0; a < 12; ++a) {
        const float fa = FF[a];
        o0 += fa * w[2 + 4 * mg + 0 + a];
        o1 += fa * w[2 + 4 * mg + 1 + a];
        o2 += fa * w[2 + 4 * mg + 2 + a];
        o3 += fa * w[2 + 4 * mg + 3 + a];
      }
      pv[mg].x = SQ2 * yv.x + o0;
      pv[mg].y = SQ2 * yv.y + o1;
      pv[mg].z = SQ2 * yv.z + o2;
      pv[mg].w = SQ2 * yv.w + o3;
    }
    __syncthreads();
#pragma unroll
    for (int mg = 0; mg < 8; ++mg) buf4[i * SG + g0 + mg] = pv[mg];
  }
  __syncthreads();

  // P5: gather even-J from p0, merge buffered odd-J, single coalesced write
#pragma unroll
  for (int k = 0; k < 16; ++k) {
    int t = tid + k * 512;
    int i2 = t >> 6;
    int j4o = t & 63;
    float ev[2];
#pragma unroll
    for (int h = 0; h < 2; ++h) {
      int me = (i2 & 1) + 2 * h;
      int jo = 4 * j4o + me;
      int J = (i2 + jo) & 255;
      int c = J >> 1;
      int r = (i2 - c) & 127;
      ev[h] = bufF[r * 132 + c];
    }
    float o0 = xodd[2 * k + 0], o1 = xodd[2 * k + 1];
    bool sw = (i2 & 1) != 0;
    float t0 = sw ? o0 : ev[0];
    float t1 = sw ? ev[0] : o0;
    float t2 = sw ? o1 : ev[1];
    float t3 = sw ? ev[1] : o1;
    xp4[t] = make_float4(t0, t1, t2, t3);
  }
}

// ---------------- Stage 2: fbrec(x0, x1, '1r', 'qper_col') -> out (8,32,256,256) -----------
// 1024 threads, 1 block/CU (LDS 130 KB). One block per output plane, 256 planes.
// LDS layout: 128 rows x 65 float4 groups (64 data + 1 pad). Row stride 260 floats.
__global__ __launch_bounds__(1024, 4) void s2_kernel(const float* __restrict__ x,
                                                     float* __restrict__ out) {
  __shared__ float bufF[128 * 260];
  float4* buf4 = reinterpret_cast<float4*>(bufF);
  constexpr int SG = 65;

  const int q = blockIdx.x;  // 0..255
  const int b = q >> 5, c = q & 31;
  const float4* x04 = reinterpret_cast<const float4*>(x + (size_t)(b * 64 + c) * 32768);
  const float4* x14 = reinterpret_cast<const float4*>(x + (size_t)(b * 64 + 32 + c) * 32768);
  float4* op4 = reinterpret_cast<float4*>(out + (size_t)q * 65536);

  const int tid = threadIdx.x;

  // P0: load x0
#pragma unroll
  for (int k = 0; k < 8; ++k) {
    int idx = tid + k * 1024;
    buf4[(idx >> 6) * SG + (idx & 63)] = x04[idx];
  }
  __syncthreads();

  // P1: vconv offset-5 (qper_col rows: wrap => column group ^32)
  {
    const int j4 = tid & 63;
    const int i0 = (tid >> 6) * 8;
    float4 acc[8];
#pragma unroll
    for (int k = 0; k < 8; ++k) acc[k] = make_float4(0.f, 0.f, 0.f, 0.f);
#pragma unroll
    for (int d = 0; d < 19; ++d) {
      int rr = i0 - 5 + d;
      int r = rr & 127;
      int g = ((unsigned)rr < 128u) ? j4 : (j4 ^ 32);
      float4 v = buf4[r * SG + g];
#pragma unroll
      for (int k = 0; k < 8; ++k) {
        int a = d - k;
        if (a >= 0 && a < 12) fma4(acc[k], FF[a], v);
      }
    }
    __syncthreads();
#pragma unroll
    for (int k = 0; k < 8; ++k) buf4[(i0 + k) * SG + j4] = acc[k];
  }
  __syncthreads();

  // P2: p1 = -1/sqrt2 * (x1 + hconv offset-5)
  {
    const int i  = tid >> 3;
    const int g0 = (tid & 7) * 8;
    float w[48];
#pragma unroll
    for (int d = 0; d < 12; ++d) {
      float4 v = buf4[i * SG + ((g0 - 2 + d) & 63)];
      w[4 * d + 0] = v.x; w[4 * d + 1] = v.y; w[4 * d + 2] = v.z; w[4 * d + 3] = v.w;
    }
    float4 pv[8];
#pragma unroll
    for (int mg = 0; mg < 8; ++mg) {
      float4 xv = x14[i * 64 + g0 + mg];
      float o0 = 0.f, o1 = 0.f, o2 = 0.f, o3 = 0.f;
#pragma unroll
      for (int a = 0; a < 12; ++a) {
        const float fa = FF[a];
        o0 += fa * w[3 + 4 * mg + 0 + a];
        o1 += fa * w[3 + 4 * mg + 1 + a];
        o2 += fa * w[3 + 4 * mg + 2 + a];
        o3 += fa * w[3 + 4 * mg + 3 + a];
      }
      pv[mg].x = NISQ2 * (xv.x + o0);
      pv[mg].y = NISQ2 * (xv.y + o1);
      pv[mg].z = NISQ2 * (xv.z + o2);
      pv[mg].w = NISQ2 * (xv.w + o3);
    }
    __syncthreads();
#pragma unroll
    for (int mg = 0; mg < 8; ++mg) buf4[i * SG + g0 + mg] = pv[mg];
  }
  __syncthreads();

  // P3: gather odd-I outputs from p1 into regs; then vconv offset-6 of p1
  float oodd[32];
  {
#pragma unroll
    for (int k = 0; k < 16; ++k) {
      int t = tid + k * 1024;
      int i2 = t >> 6;
      int j4o = t & 63;
      int m0 = 1 - (i2 & 1);
#pragma unroll
      for (int h = 0; h < 2; ++h) {
        int jo = 4 * j4o + m0 + 2 * h;
        int I = (i2 + jo) & 255;
        int r2 = I >> 1;
        int c2 = (jo - 1 - r2) & 255;
        oodd[2 * k + h] = bufF[r2 * 260 + c2];
      }
    }
    const int j4 = tid & 63;
    const int i0 = (tid >> 6) * 8;
    float4 acc[8];
#pragma unroll
    for (int k = 0; k < 8; ++k) acc[k] = make_float4(0.f, 0.f, 0.f, 0.f);
#pragma unroll
    for (int d = 0; d < 19; ++d) {
      int rr = i0 - 6 + d;
      int r = rr & 127;
      int g = ((unsigned)rr < 128u) ? j4 : (j4 ^ 32);
      float4 v = buf4[r * SG + g];
#pragma unroll
      for (int k = 0; k < 8; ++k) {
        int a = d - k;
        if (a >= 0 && a < 12) fma4(acc[k], FF[a], v);
      }
    }
    __syncthreads();
#pragma unroll
    for (int k = 0; k < 8; ++k) buf4[(i0 + k) * SG + j4] = acc[k];
  }
  __syncthreads();

  // P4: p0 = sqrt2*x0 + hconv offset-6
  {
    const int i  = tid >> 3;
    const int g0 = (tid & 7) * 8;
    float w[48];
#pragma unroll
    for (int d = 0; d < 12; ++d) {
      float4 v = buf4[i * SG + ((g0 - 2 + d) & 63)];
      w[4 * d + 0] = v.x; w[4 * d + 1] = v.y; w[4 * d + 2] = v.z; w[4 * d + 3] = v.w;
    }
    float4 pv[8];
#pragma unroll
    for (int mg = 0; mg < 8; ++mg) {
      float4 xv = x04[i * 64 + g0 + mg];
      float o0 = 0.f, o1 = 0.f, o2 = 0.f, o3 = 0.f;
#pragma unroll
      for (int a = 0; a < 12; ++a) {
        const float fa = FF[a];
        o0 += fa * w[2 + 4 * mg + 0 + a];
        o1 += fa * w[2 + 4 * mg + 1 + a];
        o2 += fa * w[2 + 4 * mg + 2 + a];
        o3 += fa * w[2 + 4 * mg + 3 + a];
      }
      pv[mg].x = SQ2 * xv.x + o0;
      pv[mg].y = SQ2 * xv.y + o1;
      pv[mg].z = SQ2 * xv.z + o2;
      pv[mg].w = SQ2 * xv.w + o3;
    }
    __syncthreads();
#pragma unroll
    for (int mg = 0; mg < 8; ++mg) buf4[i * SG + g0 + mg] = pv[mg];
  }
  __syncthreads();

  // P5: gather even-I from p0, merge buffered odd-I, single coalesced write
#pragma unroll
  for (int k = 0; k < 16; ++k) {
    int t = tid + k * 1024;
    int i2 = t >> 6;
    int j4o = t & 63;
    float ev[2];
#pragma unroll
    for (int h = 0; h < 2; ++h) {
      int me = (i2 & 1) + 2 * h;
      int jo = 4 * j4o + me;
      int I = (i2 + jo) & 255;
      int r2 = I >> 1;
      int c2 = (jo - r2) & 255;
      ev[h] = bufF[r2 * 260 + c2];
    }
    float o0 = oodd[2 * k + 0], o1 = oodd[2 * k + 1];
    bool sw = (i2 & 1) != 0;
    float t0 = sw ? o0 : ev[0];
    float t1 = sw ? ev[0] : o0;
    float t2 = sw ? o1 : ev[1];
    float t3 = sw ? ev[1] : o1;
    op4[t] = make_float4(t0, t1, t2, t3);
  }
}

extern "C" void kernel_launch(void* const* d_in, const int* in_sizes, int n_in,
                              void* d_out, int out_size, void* d_ws, size_t ws_size,
                              hipStream_t stream) {
  const float* y0 = (const float*)d_in[0];
  const float* y1 = (const float*)d_in[1];
  const float* y2 = (const float*)d_in[2];
  const float* y3 = (const float*)d_in[3];
  float* xws = (float*)d_ws;           // (8,64,128,256) fp32 = 64 MiB intermediate
  float* outp = (float*)d_out;         // (8,32,256,256) fp32

  s1_kernel<<<512, 512, 0, stream>>>(y0, y1, y2, y3, xws);
  s2_kernel<<<256, 1024, 0, stream>>>(xws, outp);
}